// Round 1
// baseline (147.651 us; speedup 1.0000x reference)
//
#include <hip/hip_runtime.h>
#include <math.h>

// CBAM pillar kernel for MI355X (gfx950) — round 16.
//
// R15 counters: VALUBusy 57%, HBM 6%, conflicts negligible.  The 57% is the
// static-schedule tail: 6250 wave-trips over 4096 resident wave slots ->
// 53% of waves run a 2nd trip while the rest idle (slot utilization 76%,
// and 0.57/0.76 ~= 0.75 peak-phase busy).  R16 = one trip per wave:
// blocks = ceil(ngroups/4) = 1563; 1024 are LDS-resident, the CP backfills
// the other 539 as blocks retire -> wall ~ 1.53x(stage+trip) instead of
// stage+2xtrip.  The next-trip prefetch / vbuf rotate / trailing drain are
// now dead and removed.  Per-trip math unchanged from R15.

#define CO 64

__device__ __forceinline__ float sgm(float x) {
  return 1.0f / (1.0f + __expf(-x));
}
template <int PAT>
__device__ __forceinline__ float qadd(float s) {
  int t = __builtin_amdgcn_update_dpp(0, __builtin_bit_cast(int, s),
                                      PAT, 0xf, 0xf, true);
  return s + __builtin_bit_cast(float, t);
}
template <int PAT>
__device__ __forceinline__ float qmaxd(float m) {
  int t = __builtin_amdgcn_update_dpp(__builtin_bit_cast(int, m),
                                      __builtin_bit_cast(int, m),
                                      PAT, 0xf, 0xf, false);
  return fmaxf(m, __builtin_bit_cast(float, t));
}
template <int PAT>
__device__ __forceinline__ float qmind(float m) {
  int t = __builtin_amdgcn_update_dpp(__builtin_bit_cast(int, m),
                                      __builtin_bit_cast(int, m),
                                      PAT, 0xf, 0xf, false);
  return fminf(m, __builtin_bit_cast(float, t));
}
// full exchange within each 4-lane quad: 0xB1=[1,0,3,2], 0x4E=[2,3,0,1]
__device__ __forceinline__ float qsum4(float s) { return qadd<0x4E>(qadd<0xB1>(s)); }
__device__ __forceinline__ float qmax4(float m) { return qmaxd<0x4E>(qmaxd<0xB1>(m)); }
__device__ __forceinline__ float qmin4(float m) { return qmind<0x4E>(qmind<0xB1>(m)); }
__device__ __forceinline__ void drain_lds() {
  __builtin_amdgcn_wave_barrier();
  __builtin_amdgcn_s_waitcnt(0xC07F);   // lgkmcnt(0)
  __builtin_amdgcn_wave_barrier();
}

// per-voxel: pvox[2p+slot] = {vf[5], bits(bin), 0, 0}  (32B records)
__global__ __launch_bounds__(256) void pack_kernel(
    const float* __restrict__ vf, const int* __restrict__ vcoord,
    const int* __restrict__ unq_inv, float* __restrict__ pvox, int n) {
  int i = blockIdx.x * blockDim.x + threadIdx.x;
  if (i >= n) return;
  int p = unq_inv[i];
  int slot = (i > 0 && unq_inv[i - 1] == p) ? 1 : 0;
  float* dst = pvox + 8 * (size_t)(2 * p + slot);
#pragma unroll
  for (int k = 0; k < 5; ++k) dst[k] = vf[5 * i + k];
  ((int*)dst)[5] = vcoord[4 * i + 1];
}

__global__ __launch_bounds__(256) void cbam_kernel(
    const float* __restrict__ pvox, const int* __restrict__ unq_cnt,
    const float* __restrict__ W1, const float* __restrict__ b1,
    const float* __restrict__ W2, const float* __restrict__ b2,
    const float* __restrict__ Wc1, const float* __restrict__ bc1,
    const float* __restrict__ Wc2, const float* __restrict__ bc2,
    const float* __restrict__ Wsp, const float* __restrict__ bsp,
    float* __restrict__ out, int U, int ngroups) {
  __shared__ __align__(16) float w2b[2048];   // 32 x 64 (stride 64)
  __shared__ __align__(16) float wc1b[1024];  // k-major: [(4k+q)*16 + j]
  __shared__ __align__(16) float wc2b[1024];  // k-major Wc2^T
  __shared__ __align__(16) float c0b[64], b2b[64], bc2b[64], bc1b[16];
  __shared__ __align__(16) float wsmx[64];    // float2[32] window sums
  __shared__ __align__(16) float wtab[16];    // float2[8] taps, [7]={0,0}
  __shared__ __align__(16) float hbuf[4][1152];  // per-wave 32 x stride 36
  __shared__ __align__(16) float vbuf[4][256];   // per-wave voxel block (1KB)

  const int tid = threadIdx.x;

  // ---- stage weights to LDS (once per block)
  for (int i = tid; i < 2048; i += 256) w2b[i] = W2[i];
  for (int i = tid; i < 1024; i += 256) {
    // i = ch*16 + j, ch = 16q + k  ->  dst (4k+q)*16 + j
    int ch = i >> 4, j = i & 15, qq = ch >> 4, k = ch & 15;
    wc1b[(4 * k + qq) * 16 + j] = Wc1[i];
    wc2b[(4 * k + qq) * 16 + j] = Wc2[j * 64 + ch];
  }
  if (tid < 64) { b2b[tid] = b2[tid]; bc2b[tid] = bc2[tid]; }
  if (tid < 16) bc1b[tid] = bc1[tid];
  if (tid < 32) {
    float sm = 0.0f, sx = 0.0f;
    for (int k = 0; k < 7; ++k)
      if ((unsigned)(tid + k - 3) < 32u) { sm += Wsp[k]; sx += Wsp[7 + k]; }
    wsmx[2 * tid] = sm; wsmx[2 * tid + 1] = sx;
  }
  if (tid < 8) {
    float a = 0.0f, b = 0.0f;
    if (tid < 7) { a = Wsp[tid]; b = Wsp[7 + tid]; }
    wtab[2 * tid] = a; wtab[2 * tid + 1] = b;
  }
  __syncthreads();
  if (tid < 64) {                      // c0[ch] = b2 + relu(b1) @ W2
    float c = b2b[tid];
    for (int j = 0; j < 32; ++j) c += fmaxf(b1[j], 0.0f) * w2b[j * 64 + tid];
    c0b[tid] = c;
  }
  __syncthreads();

  const int wv = tid >> 6, lane = tid & 63;

  // one group (16 pillars) per wave; no grid-stride loop.
  const int grp = blockIdx.x * 4 + wv;
  if (grp >= ngroups) return;          // all __syncthreads are above

  float* const hb = hbuf[wv];
  float* const vb = vbuf[wv];
  float4* const vb4 = (float4*)vb;

  // phase-1 constants
  const int j32 = lane & 31, vh = lane >> 5;
  float w1r[5];
#pragma unroll
  for (int i = 0; i < 5; ++i) w1r[i] = W1[i * 32 + j32];
  const float b1r = b1[j32];

  const int q = lane & 3, pp = lane >> 2;
  const float4* pv4 = (const float4*)pvox;
  const int f4max = 4 * U - 1;         // pvox has 4U float4 entries

  // ---- stage this wave's voxel block (one coalesced 1KB load)
  {
    int idx = 64 * grp + lane;
    idx = idx < f4max ? idx : f4max;
    vb4[lane] = pv4[idx];
  }
  drain_lds();

  const int P0 = grp * 16;             // 16 pillars this trip

  // ---- metadata (cnt global; bins from vbuf)
  const int pg = P0 + pp;
  const int pc = pg < U ? pg : (U - 1);
  const int cnt = unq_cnt[pc];
  const int* vbi = (const int*)vb;
  const int b0 = vbi[(2 * pp) * 8 + 5] & 31;
  const int b1raw = vbi[(2 * pp + 1) * 8 + 5];

  // ---- phase 1: layer1 from vbuf.  lane = (j32, voxel-half vh)
  {
    const float4* vb4c = (const float4*)vb;
#pragma unroll
    for (int v = 0; v < 16; ++v) {
      const int rec = 16 * vh + v;
      float4 g1 = vb4c[2 * rec];       // uniform per half -> broadcast
      float4 g2 = vb4c[2 * rec + 1];
      float h = b1r + g1.x * w1r[0] + g1.y * w1r[1] + g1.z * w1r[2] +
                g1.w * w1r[3] + g2.x * w1r[4];
      const int row = (v & 1) * 16 + 8 * vh + (v >> 1);
      hb[row * 36 + j32] = fmaxf(h, 0.0f);
    }
  }
  drain_lds();

  // ---- phase 2: lane = (pillar pp, ch-quad q); channels 16q..16q+15
  const bool has2 = (cnt >= 2);
  const int b1e = has2 ? (b1raw & 31) : 64;

  // layer2
  float y0[16], y1[16];
  const float4* b2b4 = (const float4*)b2b;
#pragma unroll
  for (int kb = 0; kb < 4; ++kb) {
    float4 w = b2b4[q * 4 + kb];
    y0[4 * kb] = w.x; y0[4 * kb + 1] = w.y; y0[4 * kb + 2] = w.z; y0[4 * kb + 3] = w.w;
    y1[4 * kb] = w.x; y1[4 * kb + 1] = w.y; y1[4 * kb + 2] = w.z; y1[4 * kb + 3] = w.w;
  }
  const float4* hb4 = (const float4*)hb;
  const float4* w2b4 = (const float4*)w2b;
  float4 h0c = hb4[pp * 9];
  float4 h1c = hb4[(16 + pp) * 9];
#pragma unroll
  for (int jb = 0; jb < 8; ++jb) {
    float4 h0n, h1n;
    if (jb < 7) {
      h0n = hb4[pp * 9 + jb + 1];
      h1n = hb4[(16 + pp) * 9 + jb + 1];
    }
    float h0a[4] = {h0c.x, h0c.y, h0c.z, h0c.w};
    float h1a[4] = {h1c.x, h1c.y, h1c.z, h1c.w};
#pragma unroll
    for (int jj = 0; jj < 4; ++jj) {
      const int j = 4 * jb + jj;
#pragma unroll
      for (int kb = 0; kb < 4; ++kb) {
        float4 w = w2b4[16 * j + 4 * q + kb];  // q 2-way banks: free
        y0[4 * kb]     += h0a[jj] * w.x; y0[4 * kb + 1] += h0a[jj] * w.y;
        y0[4 * kb + 2] += h0a[jj] * w.z; y0[4 * kb + 3] += h0a[jj] * w.w;
        y1[4 * kb]     += h1a[jj] * w.x; y1[4 * kb + 1] += h1a[jj] * w.y;
        y1[4 * kb + 2] += h1a[jj] * w.z; y1[4 * kb + 3] += h1a[jj] * w.w;
      }
    }
    h0c = h0n; h1c = h1n;
  }
#pragma unroll
  for (int k = 0; k < 16; ++k) y1[k] = has2 ? y1[k] : y0[k];

  // pooled stats + chMLP layer1 partials (thread-local over 16 ch)
  float ha[16] = {0}, hm[16] = {0};
  const float kf = has2 ? 30.0f : 31.0f;     // 32 - nocc
  const float inv32 = 1.0f / 32.0f;
  const float4* c04 = (const float4*)c0b;
  const float4* wc14 = (const float4*)wc1b;
#pragma unroll
  for (int kb = 0; kb < 4; ++kb) {
    float4 cq = c04[q * 4 + kb];
    float c0a[4] = {cq.x, cq.y, cq.z, cq.w};
#pragma unroll
    for (int i = 0; i < 4; ++i) {
      const int k = 4 * kb + i;
      const float c0v = c0a[i];
      const float sumy = y0[k] + (has2 ? y1[k] : 0.0f);
      const float avg = fmaf(c0v, kf, sumy) * inv32;
      const float mxv = fmaxf(fmaxf(y0[k], y1[k]), c0v);
#pragma unroll
      for (int jb = 0; jb < 4; ++jb) {
        float4 w = wc14[(4 * k + q) * 4 + jb];   // k-major: q 2-way, free
        ha[4 * jb]     += avg * w.x; ha[4 * jb + 1] += avg * w.y;
        ha[4 * jb + 2] += avg * w.z; ha[4 * jb + 3] += avg * w.w;
        hm[4 * jb]     += mxv * w.x; hm[4 * jb + 1] += mxv * w.y;
        hm[4 * jb + 2] += mxv * w.z; hm[4 * jb + 3] += mxv * w.w;
      }
    }
  }
  // quad-reduce partials, bias, relu, combine pools
  float g[16];
  const float4* bc14 = (const float4*)bc1b;
#pragma unroll
  for (int jb = 0; jb < 4; ++jb) {
    float4 bb = bc14[jb];
    float bba[4] = {bb.x, bb.y, bb.z, bb.w};
#pragma unroll
    for (int i = 0; i < 4; ++i) {
      const int j = 4 * jb + i;
      const float sa = qsum4(ha[j]) + bba[i];
      const float sm = qsum4(hm[j]) + bba[i];
      g[j] = fmaxf(sa, 0.0f) + fmaxf(sm, 0.0f);
    }
  }

  // chMLP layer2 -> attc; bin-column partial reductions
  float attc[16];
  float sc = 0.0f, mc = -3.0e38f;
  float sy0 = 0.0f, my0 = -3.0e38f, sy1 = 0.0f, my1 = -3.0e38f;
  const float4* wc24 = (const float4*)wc2b;
  const float4* bc24 = (const float4*)bc2b;
#pragma unroll
  for (int kb = 0; kb < 4; ++kb) {
    float4 cq = c04[q * 4 + kb];
    float4 bq = bc24[q * 4 + kb];
    float c0a[4] = {cq.x, cq.y, cq.z, cq.w};
    float b2a[4] = {bq.x, bq.y, bq.z, bq.w};
#pragma unroll
    for (int i = 0; i < 4; ++i) {
      const int k = 4 * kb + i;
      float pre = 2.0f * b2a[i];
#pragma unroll
      for (int jb = 0; jb < 4; ++jb) {
        float4 w = wc24[(4 * k + q) * 4 + jb];
        pre += g[4 * jb] * w.x + g[4 * jb + 1] * w.y +
               g[4 * jb + 2] * w.z + g[4 * jb + 3] * w.w;
      }
      const float a = sgm(pre);
      attc[k] = a;
      const float pc0 = a * c0a[i], py0 = a * y0[k], py1 = a * y1[k];
      sc += pc0;  mc = fmaxf(mc, pc0);
      sy0 += py0; my0 = fmaxf(my0, py0);
      sy1 += py1; my1 = fmaxf(my1, py1);
    }
  }
  sc = qsum4(sc);   mc = qmax4(mc);
  sy0 = qsum4(sy0); my0 = qmax4(my0);
  sy1 = qsum4(sy1); my1 = qmax4(my1);

  // analytic conv over 32 bins, 8 bins per lane, quad-combined
  const float inv64 = 1.0f / 64.0f;
  const float Mn = sc * inv64, Mx = mc;
  const float dm0 = (sy0 - sc) * inv64, dx0 = my0 - mc;
  const float dm1 = (sy1 - sc) * inv64, dx1 = my1 - mc;
  const float bspr = bsp[0];
  const float2* ws2 = (const float2*)wsmx;
  const float2* wt2 = (const float2*)wtab;
  float maxE = -3.0e38f, minE = 3.0e38f, sv0 = -3.0e38f, sv1 = -3.0e38f;
#pragma unroll
  for (int k = 0; k < 8; ++k) {
    const int b = 8 * q + k;
    float2 ws = ws2[b];
    float acc = bspr + Mn * ws.x + Mx * ws.y;
    int k0 = b0 - b + 3;  k0 = ((unsigned)k0 <= 6u) ? k0 : 7;
    int k1 = b1e - b + 3; k1 = ((unsigned)k1 <= 6u) ? k1 : 7;
    float2 w0 = wt2[k0];
    float2 w1v = wt2[k1];
    acc += dm0 * w0.x + dx0 * w0.y + dm1 * w1v.x + dx1 * w1v.y;
    const bool o0 = (b == b0), o1 = (b == b1e);
    const bool oc = o0 || o1;
    maxE = fmaxf(maxE, oc ? -3.0e38f : acc);
    minE = fminf(minE, oc ?  3.0e38f : acc);
    sv0 = o0 ? acc : sv0;
    sv1 = o1 ? acc : sv1;
  }
  maxE = qmax4(maxE); minE = qmin4(minE);
  sv0 = qmax4(sv0);   sv1 = qmax4(sv1);
  const float sig0 = sgm(sv0);
  const float sig1 = has2 ? sgm(sv1) : sig0;
  const float sE = sgm(maxE), sI = sgm(minE);

  // epilogue: final max over bins, stores
  if (pg < U) {
    float4* ov = (float4*)(out + (size_t)pg * CO + 16 * q);
#pragma unroll
    for (int kb = 0; kb < 4; ++kb) {
      float4 cq = c04[q * 4 + kb];
      float c0a[4] = {cq.x, cq.y, cq.z, cq.w};
      float rr[4];
#pragma unroll
      for (int i = 0; i < 4; ++i) {
        const int k = 4 * kb + i;
        const float c0v = c0a[i];
        const float sel = (c0v >= 0.0f) ? sE : sI;
        const float m = fmaxf(fmaxf(y0[k] * sig0, y1[k] * sig1), c0v * sel);
        rr[i] = attc[k] * m;
      }
      float4 r; r.x = rr[0]; r.y = rr[1]; r.z = rr[2]; r.w = rr[3];
      ov[kb] = r;
    }
    if (q == 0) out[(size_t)U * CO + pg] = has2 ? 1.0f : 0.0f;
  }
}

extern "C" void kernel_launch(void* const* d_in, const int* in_sizes, int n_in,
                              void* d_out, int out_size, void* d_ws, size_t ws_size,
                              hipStream_t stream) {
  const float* vf      = (const float*)d_in[0];
  const int*   vcoord  = (const int*)d_in[1];
  // d_in[2] = unq_coords (unused: identity)
  const int*   unq_inv = (const int*)d_in[3];
  const int*   unq_cnt = (const int*)d_in[4];
  const float* W1  = (const float*)d_in[5];
  const float* b1  = (const float*)d_in[6];
  const float* W2  = (const float*)d_in[7];
  const float* b2  = (const float*)d_in[8];
  const float* Wc1 = (const float*)d_in[9];
  const float* bc1 = (const float*)d_in[10];
  const float* Wc2 = (const float*)d_in[11];
  const float* bc2 = (const float*)d_in[12];
  const float* Wsp = (const float*)d_in[13];
  const float* bsp = (const float*)d_in[14];

  const int N = in_sizes[3];   // voxels
  const int U = in_sizes[4];   // pillars

  float* pvox = (float*)d_ws;  // 2U records x 32B (6.4 MB @ U=100k)

  pack_kernel<<<(N + 255) / 256, 256, 0, stream>>>(vf, vcoord, unq_inv, pvox, N);

  const int ngroups = (U + 15) / 16;      // 16 pillars per wave
  const int blocks = (ngroups + 3) / 4;   // exactly 1 trip per wave
  cbam_kernel<<<blocks, 256, 0, stream>>>(
      pvox, unq_cnt, W1, b1, W2, b2, Wc1, bc1, Wc2, bc2, Wsp, bsp,
      (float*)d_out, U, ngroups);
}